// Round 1
// baseline (97.065 us; speedup 1.0000x reference)
//
#include <hip/hip_runtime.h>

#define LEN_C 1024
#define LR_F 0.01f
#define GAMMA_F 0.999f
// R*S = 16, E = 4

// Kernel 1: err[e] = Dis[e, LEN_C-1] - sum_{rs,n} Fx[rs,e,n] * w0[rs,n]
__global__ __launch_bounds__(256) void k_error(const float* __restrict__ Fx,
                                               const float* __restrict__ Dis,
                                               const float* __restrict__ w0,
                                               float* __restrict__ err) {
    int e = blockIdx.x;      // 0..3
    int tid = threadIdx.x;   // 0..255
    float acc = 0.f;
    for (int i = tid; i < 16 * LEN_C; i += 256) {
        int rs = i >> 10;
        int n  = i & (LEN_C - 1);
        acc += Fx[rs * (4 * LEN_C) + e * LEN_C + n] * w0[rs * LEN_C + n];
    }
    for (int off = 32; off > 0; off >>= 1)
        acc += __shfl_down(acc, off, 64);
    __shared__ float s[4];
    int lane = tid & 63, w = tid >> 6;
    if (lane == 0) s[w] = acc;
    __syncthreads();
    if (tid == 0) {
        float anti = s[0] + s[1] + s[2] + s[3];
        err[e] = Dis[e * LEN_C + (LEN_C - 1)] - anti;
    }
}

// Kernel 2: cw[rs,n] = w0[rs,n] + LR * sum_e Fx[rs,e,n]*err[e]; also gamma.
__global__ __launch_bounds__(256) void k_cw_gamma(const float* __restrict__ Fx,
                                                  const float* __restrict__ w0,
                                                  const float* __restrict__ err,
                                                  float* __restrict__ cw,
                                                  float* __restrict__ out_gamma) {
    int gid = blockIdx.x * 256 + threadIdx.x;   // 0..16383
    int rs = gid >> 10;
    int n  = gid & (LEN_C - 1);
    float e0 = err[0], e1 = err[1], e2 = err[2], e3 = err[3];
    const float* fx = Fx + rs * (4 * LEN_C) + n;
    float s = fx[0] * e0 + fx[LEN_C] * e1 + fx[2 * LEN_C] * e2 + fx[3 * LEN_C] * e3;
    cw[gid] = w0[gid] + LR_F * s;
    if (gid < LEN_C) {
        out_gamma[gid] = powf(GAMMA_F, (float)(LEN_C - 1 - gid));
    }
}

// Kernel 3: out[t,e] += sum_rs sum_{n in tile} Fx[rs,e,t-n] * cw[rs,n]
// Grid: 4 e * { Tb in 0..3 (t-tiles of 256), Nb in 0..4*Tb+3 (n-tiles of 64) } = 160 blocks.
// Per block: stage the needed Fx band (16 rs x 320) in LDS; each lane owns 4
// consecutive t, slides a 2x float4 register window over Fx so one ds_read_b128
// feeds ~16 FMAs. 4 waves cover 4 rs each; LDS reduce; atomicAdd to out.
__global__ __launch_bounds__(256) void k_conv(const float* __restrict__ Fx,
                                              const float* __restrict__ cw,
                                              float* __restrict__ out) {
    int bid = blockIdx.x;   // 0..159
    int e = bid / 40;
    int r = bid % 40;
    int Tb, Nb;
    if (r < 4)       { Tb = 0; Nb = r; }
    else if (r < 12) { Tb = 1; Nb = r - 4; }
    else if (r < 24) { Tb = 2; Nb = r - 12; }
    else             { Tb = 3; Nb = r - 24; }
    const int T0 = Tb * 256, N0 = Nb * 64;
    const int B = T0 - N0 - 63;   // sFx[rs][m] = Fx[rs,e,B+m], m in [0,320)

    __shared__ __align__(16) float sFx[16 * 320];   // 20 KiB
    int tid = threadIdx.x;
    for (int rs = 0; rs < 16; ++rs) {
        const float* src = Fx + (rs * 4 + e) * LEN_C;
        for (int m = tid; m < 320; m += 256) {
            int k = B + m;
            sFx[rs * 320 + m] = ((unsigned)k < (unsigned)LEN_C) ? src[k] : 0.f;
        }
    }
    __syncthreads();

    int w = tid >> 6, l = tid & 63;
    int i0 = l * 4;   // lane owns t = T0 + i0 .. T0 + i0 + 3
    float acc0 = 0.f, acc1 = 0.f, acc2 = 0.f, acc3 = 0.f;

    #pragma unroll
    for (int rr = 0; rr < 4; ++rr) {
        int rs = w * 4 + rr;
        const float* crow = cw + rs * LEN_C + N0;
        const float* frow = sFx + rs * 320;
        int M = i0 + 60;                         // window base for jb=0
        float4 flo = *(const float4*)(frow + M);
        float4 fhi = *(const float4*)(frow + M + 4);
        #pragma unroll
        for (int jb = 0; jb < 16; ++jb) {
            float4 c = *(const float4*)(crow + jb * 4);
            float v0 = flo.x, v1 = flo.y, v2 = flo.z, v3 = flo.w;
            float v4 = fhi.x, v5 = fhi.y, v6 = fhi.z;
            // acc[a] += sFx[M + a - jj + 3] * c[jj]
            acc0 += v3 * c.x + v2 * c.y + v1 * c.z + v0 * c.w;
            acc1 += v4 * c.x + v3 * c.y + v2 * c.z + v1 * c.w;
            acc2 += v5 * c.x + v4 * c.y + v3 * c.z + v2 * c.w;
            acc3 += v6 * c.x + v5 * c.y + v4 * c.z + v3 * c.w;
            // slide window down by 4
            fhi = flo;
            M -= 4;
            if (jb < 15) flo = *(const float4*)(frow + M);
        }
    }

    __syncthreads();              // all waves done reading sFx
    float* sred = sFx;            // reuse LDS: [4 waves][256 t]
    sred[w * 256 + i0 + 0] = acc0;
    sred[w * 256 + i0 + 1] = acc1;
    sred[w * 256 + i0 + 2] = acc2;
    sred[w * 256 + i0 + 3] = acc3;
    __syncthreads();
    int i = tid;
    float sum = sred[i] + sred[256 + i] + sred[512 + i] + sred[768 + i];
    atomicAdd(&out[(T0 + i) * 4 + e], sum);
}

extern "C" void kernel_launch(void* const* d_in, const int* in_sizes, int n_in,
                              void* d_out, int out_size, void* d_ws, size_t ws_size,
                              hipStream_t stream) {
    const float* Fx  = (const float*)d_in[0];   // [4,4,4,1024]
    const float* Dis = (const float*)d_in[1];   // [4,1024]
    const float* w0  = (const float*)d_in[2];   // [4,4,1024]
    float* out = (float*)d_out;                 // [1024*4] anti_noise + [1024] gamma
    float* err = (float*)d_ws;                  // 4 floats
    float* cw  = (float*)d_ws + 64;             // 16384 floats

    hipMemsetAsync(d_out, 0, (size_t)out_size * sizeof(float), stream);
    k_error<<<4, 256, 0, stream>>>(Fx, Dis, w0, err);
    k_cw_gamma<<<64, 256, 0, stream>>>(Fx, w0, err, cw, out + 4 * LEN_C);
    k_conv<<<160, 256, 0, stream>>>(Fx, cw, out);
}

// Round 2
// 73.664 us; speedup vs baseline: 1.3177x; 1.3177x over previous
//
#include <hip/hip_runtime.h>

#define LEN_C 1024
#define LR_F 0.01f
#define GAMMA_F 0.999f
// R*S = 16, E = 4

// Single fused kernel. Grid: 160 blocks = 4 e * { Tb in 0..3 (t-tiles of 256),
// Nb in 0..4*Tb+3 (n-tiles of 64) }. Each block:
//   Phase A: stage Fx band [16 rs x 320] for (e, Tb, Nb) into LDS.
//   Phase B: redundantly compute err[e'] = Dis[e',1023] - sum_{rs,n} Fx*w0
//            (float4 loads, wave shuffle-reduce, 4-wave LDS combine).
//   Phase C: build cw tile [16 rs x 64 n] in LDS:
//            cw = w0 + LR * sum_e' Fx[rs,e',n]*err[e'].
//   Phase D: sliding-register-window causal conv (16 FMA per ds_read_b128).
//   Phase E: 4-wave LDS reduce, one atomicAdd per output.
// Blocks 0..3 additionally write gamma_vector (independent of everything).
__global__ __launch_bounds__(256) void k_fused(const float* __restrict__ Fx,
                                               const float* __restrict__ Dis,
                                               const float* __restrict__ w0,
                                               float* __restrict__ out) {
    int bid = blockIdx.x;   // 0..159
    int tid = threadIdx.x;  // 0..255
    int e = bid / 40;
    int r = bid % 40;
    int Tb, Nb;
    if (r < 4)       { Tb = 0; Nb = r; }
    else if (r < 12) { Tb = 1; Nb = r - 4; }
    else if (r < 24) { Tb = 2; Nb = r - 12; }
    else             { Tb = 3; Nb = r - 24; }
    const int T0 = Tb * 256, N0 = Nb * 64;
    const int B = T0 - N0 - 63;   // sFx[rs][m] = Fx[rs,e,B+m], m in [0,320)

    __shared__ __align__(16) float sFx[16 * 320];   // 20 KiB (reused for reduce)
    __shared__ __align__(16) float sCw[16 * 64];    // 4 KiB
    __shared__ float sPart[4][4];                   // [wave][e']
    __shared__ float sErr[4];

    // gamma (blocks 0..3; no sync needed, disjoint output region)
    if (bid < 4) {
        int g = bid * 256 + tid;
        out[4 * LEN_C + g] = powf(GAMMA_F, (float)(LEN_C - 1 - g));
    }

    // ---- Phase A: stage Fx band ----
    for (int rs = 0; rs < 16; ++rs) {
        const float* src = Fx + (rs * 4 + e) * LEN_C;
        for (int m = tid; m < 320; m += 256) {
            int k = B + m;
            sFx[rs * 320 + m] = ((unsigned)k < (unsigned)LEN_C) ? src[k] : 0.f;
        }
    }

    // ---- Phase B: redundant err computation ----
    float a0 = 0.f, a1 = 0.f, a2 = 0.f, a3 = 0.f;
    #pragma unroll 4
    for (int i = tid; i < 4096; i += 256) {      // float4 index over (rs, n/4)
        int rs = i >> 8;                         // 256 float4 per rs row
        int n4 = i & 255;
        const float4* fx = (const float4*)(Fx + rs * (4 * LEN_C)) + n4;
        float4 wv = ((const float4*)(w0 + rs * LEN_C))[n4];
        float4 f0 = fx[0], f1 = fx[256], f2 = fx[512], f3 = fx[768];
        a0 += f0.x * wv.x + f0.y * wv.y + f0.z * wv.z + f0.w * wv.w;
        a1 += f1.x * wv.x + f1.y * wv.y + f1.z * wv.z + f1.w * wv.w;
        a2 += f2.x * wv.x + f2.y * wv.y + f2.z * wv.z + f2.w * wv.w;
        a3 += f3.x * wv.x + f3.y * wv.y + f3.z * wv.z + f3.w * wv.w;
    }
    for (int off = 32; off > 0; off >>= 1) {
        a0 += __shfl_down(a0, off, 64);
        a1 += __shfl_down(a1, off, 64);
        a2 += __shfl_down(a2, off, 64);
        a3 += __shfl_down(a3, off, 64);
    }
    int w = tid >> 6, l = tid & 63;
    if (l == 0) { sPart[w][0] = a0; sPart[w][1] = a1; sPart[w][2] = a2; sPart[w][3] = a3; }
    __syncthreads();
    if (tid < 4) {
        float anti = sPart[0][tid] + sPart[1][tid] + sPart[2][tid] + sPart[3][tid];
        sErr[tid] = Dis[tid * LEN_C + (LEN_C - 1)] - anti;
    }
    __syncthreads();

    // ---- Phase C: cw tile for n in [N0, N0+64) ----
    {
        int rs = tid >> 4, j4 = (tid & 15) * 4;
        int n = N0 + j4;
        const float* base = Fx + rs * (4 * LEN_C) + n;
        float4 wv = *(const float4*)(w0 + rs * LEN_C + n);
        float4 f0 = *(const float4*)(base);
        float4 f1 = *(const float4*)(base + LEN_C);
        float4 f2 = *(const float4*)(base + 2 * LEN_C);
        float4 f3 = *(const float4*)(base + 3 * LEN_C);
        float e0 = sErr[0], e1 = sErr[1], e2 = sErr[2], e3 = sErr[3];
        float4 c;
        c.x = wv.x + LR_F * (f0.x * e0 + f1.x * e1 + f2.x * e2 + f3.x * e3);
        c.y = wv.y + LR_F * (f0.y * e0 + f1.y * e1 + f2.y * e2 + f3.y * e3);
        c.z = wv.z + LR_F * (f0.z * e0 + f1.z * e1 + f2.z * e2 + f3.z * e3);
        c.w = wv.w + LR_F * (f0.w * e0 + f1.w * e1 + f2.w * e2 + f3.w * e3);
        *(float4*)(sCw + rs * 64 + j4) = c;
    }
    __syncthreads();   // sFx (Phase A) + sCw ready

    // ---- Phase D: sliding-window conv ----
    int i0 = l * 4;   // lane owns t = T0 + i0 .. T0 + i0 + 3
    float acc0 = 0.f, acc1 = 0.f, acc2 = 0.f, acc3 = 0.f;
    #pragma unroll
    for (int rr = 0; rr < 4; ++rr) {
        int rs = w * 4 + rr;
        const float* crow = sCw + rs * 64;       // wave-uniform -> LDS broadcast
        const float* frow = sFx + rs * 320;
        int M = i0 + 60;
        float4 flo = *(const float4*)(frow + M);
        float4 fhi = *(const float4*)(frow + M + 4);
        #pragma unroll
        for (int jb = 0; jb < 16; ++jb) {
            float4 c = *(const float4*)(crow + jb * 4);
            float v0 = flo.x, v1 = flo.y, v2 = flo.z, v3 = flo.w;
            float v4 = fhi.x, v5 = fhi.y, v6 = fhi.z;
            acc0 += v3 * c.x + v2 * c.y + v1 * c.z + v0 * c.w;
            acc1 += v4 * c.x + v3 * c.y + v2 * c.z + v1 * c.w;
            acc2 += v5 * c.x + v4 * c.y + v3 * c.z + v2 * c.w;
            acc3 += v6 * c.x + v5 * c.y + v4 * c.z + v3 * c.w;
            fhi = flo;
            M -= 4;
            if (jb < 15) flo = *(const float4*)(frow + M);
        }
    }

    // ---- Phase E: cross-wave reduce + atomic ----
    __syncthreads();              // all waves done reading sFx/sCw
    float* sred = sFx;            // reuse LDS: [4 waves][256 t]
    sred[w * 256 + i0 + 0] = acc0;
    sred[w * 256 + i0 + 1] = acc1;
    sred[w * 256 + i0 + 2] = acc2;
    sred[w * 256 + i0 + 3] = acc3;
    __syncthreads();
    float sum = sred[tid] + sred[256 + tid] + sred[512 + tid] + sred[768 + tid];
    atomicAdd(&out[(T0 + tid) * 4 + e], sum);
}

extern "C" void kernel_launch(void* const* d_in, const int* in_sizes, int n_in,
                              void* d_out, int out_size, void* d_ws, size_t ws_size,
                              hipStream_t stream) {
    const float* Fx  = (const float*)d_in[0];   // [4,4,4,1024]
    const float* Dis = (const float*)d_in[1];   // [4,1024]
    const float* w0  = (const float*)d_in[2];   // [4,4,1024]
    float* out = (float*)d_out;                 // [1024*4] anti_noise + [1024] gamma

    // zero only the atomic-accumulated region; gamma is written directly
    hipMemsetAsync(d_out, 0, 4 * LEN_C * sizeof(float), stream);
    k_fused<<<160, 256, 0, stream>>>(Fx, Dis, w0, out);
}